// Round 2
// baseline (336.308 us; speedup 1.0000x reference)
//
#include <hip/hip_runtime.h>
#include <hip/hip_bf16.h>

// LRU forward, bf16-MFMA pipeline.
//  drive = gamma*(X@B^T)+bias_h (complex); h_t = lam*h_{t-1}+d_t;
//  Y = Re(H@C^T) + X@D^T + bias_out.
// Structure:
//  k_params : lam, gamma, lam^64 (f32, small)
//  k_prep_w : Bcat=[Bre;Bim] bf16 [1024][256]; Ccat=[Cre|-Cim|D] bf16 [256][1280]
//  k_prep_x : X f32 -> Xb bf16 [65536][256]
//  k_gemm1  : bf16 MFMA, M=65536 N=1024 K=256, epilogue gamma/bias -> Hbuf (drive)
//  k_scanF  : per-chunk (L=64) local-scan finals (read-only)
//  k_carry  : carry chain across 64 chunks per (b,h) in f32
//  k_scanW  : re-scan each chunk from exact f32 carry, overwrite Hbuf with H
//  k_gemm2  : bf16 MFMA, M=65536 N=256 K=1280 (A=[Hre|Him|Xb]), +bias -> Y f32
// ws total ~170 MiB (previous round bailed: need 277MB > ws, output stayed 0).

#define TT     4096
#define BATCHN 16
#define MM     (BATCHN * TT)
#define LCH    64
#define NCH    (TT / LCH)

typedef unsigned short u16;
typedef short bf16x8 __attribute__((ext_vector_type(8)));
typedef float f32x4 __attribute__((ext_vector_type(4)));

__device__ __forceinline__ u16 f2bf(float f) {
  union { __hip_bfloat16 b; u16 u; } cv;
  cv.b = __float2bfloat16(f);
  return cv.u;
}
__device__ __forceinline__ float bf2f(u16 u) {
  union { u16 u; __hip_bfloat16 b; } cv;
  cv.u = u;
  return __bfloat162float(cv.b);
}

// ---------------- params ----------------
__global__ void k_params(const float* __restrict__ nu_log,
                         const float* __restrict__ theta_log,
                         float* __restrict__ P) {
  int h = threadIdx.x;
  if (h >= 512) return;
  double nu  = exp((double)nu_log[h]);
  double th  = exp((double)theta_log[h]);
  double mag = exp(-nu);
  double g   = sqrt(fmax(0.0, 1.0 - mag * mag));
  double magL = exp(-(double)LCH * nu);
  double aL   = (double)LCH * th;
  P[h]        = (float)(mag * cos(th));   // lam_re
  P[512 + h]  = (float)(mag * sin(th));   // lam_im
  P[1024 + h] = (float)g;                 // gamma
  P[1536 + h] = (float)(magL * cos(aL));  // lam^L re
  P[2048 + h] = (float)(magL * sin(aL));  // lam^L im
}

// ---------------- weight prep (bf16 concat) ----------------
__global__ void k_prep_w(const float* __restrict__ Bre, const float* __restrict__ Bim,
                         const float* __restrict__ Cre, const float* __restrict__ Cim,
                         const float* __restrict__ D, u16* __restrict__ Bcat,
                         u16* __restrict__ Ccat) {
  const int NB = 1024 * 256;          // Bcat elems
  const int NC = 256 * 1280;          // Ccat elems
  for (int idx = blockIdx.x * blockDim.x + threadIdx.x; idx < NB + NC;
       idx += gridDim.x * blockDim.x) {
    if (idx < NB) {
      int row = idx >> 8, col = idx & 255;
      float v = (row < 512) ? Bre[row * 256 + col] : Bim[(row - 512) * 256 + col];
      Bcat[idx] = f2bf(v);
    } else {
      int j = idx - NB;
      int row = j / 1280, col = j % 1280;
      float v;
      if (col < 512)       v =  Cre[row * 512 + col];
      else if (col < 1024) v = -Cim[row * 512 + (col - 512)];
      else                 v =  D[row * 256 + (col - 1024)];
      Ccat[j] = f2bf(v);
    }
  }
}

// ---------------- X -> bf16 ----------------
__global__ __launch_bounds__(256) void k_prep_x(const float* __restrict__ X,
                                                u16* __restrict__ Xb) {
  int idx = blockIdx.x * 256 + threadIdx.x;  // 0 .. 2M-1, 8 elems each
  const float4* s = (const float4*)X + (size_t)idx * 2;
  float4 a = s[0], b = s[1];
  u16 o[8] = {f2bf(a.x), f2bf(a.y), f2bf(a.z), f2bf(a.w),
              f2bf(b.x), f2bf(b.y), f2bf(b.z), f2bf(b.w)};
  *(int4*)(Xb + (size_t)idx * 8) = *(const int4*)o;
}

// ---------------- GEMM1: Hbuf(drive) = epi(Xb @ Bcat^T) ----------------
// 128x128 tile, BK=64, 4 waves (2x2), 16x16x32 MFMA, XOR slot swizzle.
__global__ __launch_bounds__(256) void k_gemm1(
    const u16* __restrict__ Xb, const u16* __restrict__ Bcat,
    const float* __restrict__ P, const float* __restrict__ bhr,
    const float* __restrict__ bhi, u16* __restrict__ Hbuf) {
  __shared__ __align__(16) char smem[2 * 128 * 64 * 2];
  char* sA = smem;
  char* sB = smem + 128 * 64 * 2;
  const int tid = threadIdx.x;
  const int lane = tid & 63;
  const int wid = tid >> 6;
  const int wr = wid >> 1, wc = wid & 1;
  const int mb = blockIdx.x * 128;
  const int nb = blockIdx.y * 128;

  f32x4 acc[4][4];
#pragma unroll
  for (int r = 0; r < 4; ++r)
#pragma unroll
    for (int c = 0; c < 4; ++c) acc[r][c] = (f32x4)0.f;

  for (int kt = 0; kt < 4; ++kt) {
    const int k0 = kt * 64;
    __syncthreads();
#pragma unroll
    for (int i = 0; i < 4; ++i) {
      int s = i * 256 + tid;
      int row = s >> 3, slot = s & 7;
      int4 va = *(const int4*)(Xb + (size_t)(mb + row) * 256 + k0 + slot * 8);
      int4 vb = *(const int4*)(Bcat + (size_t)(nb + row) * 256 + k0 + slot * 8);
      int soff = row * 128 + ((slot ^ (row & 7)) << 4);
      *(int4*)(sA + soff) = va;
      *(int4*)(sB + soff) = vb;
    }
    __syncthreads();
#pragma unroll
    for (int kk = 0; kk < 2; ++kk) {
      bf16x8 af[4], bfr[4];
#pragma unroll
      for (int r = 0; r < 4; ++r) {
        int row = wr * 64 + r * 16 + (lane & 15);
        int slot = (kk * 4 + (lane >> 4)) ^ (row & 7);
        af[r] = *(const bf16x8*)(sA + row * 128 + slot * 16);
      }
#pragma unroll
      for (int c = 0; c < 4; ++c) {
        int row = wc * 64 + c * 16 + (lane & 15);
        int slot = (kk * 4 + (lane >> 4)) ^ (row & 7);
        bfr[c] = *(const bf16x8*)(sB + row * 128 + slot * 16);
      }
#pragma unroll
      for (int r = 0; r < 4; ++r)
#pragma unroll
        for (int c = 0; c < 4; ++c)
          acc[r][c] = __builtin_amdgcn_mfma_f32_16x16x32_bf16(af[r], bfr[c],
                                                              acc[r][c], 0, 0, 0);
    }
  }
  const int rbase = (lane >> 4) * 4;
  const int cbase = lane & 15;
#pragma unroll
  for (int r = 0; r < 4; ++r)
#pragma unroll
    for (int c = 0; c < 4; ++c) {
      int col = nb + wc * 64 + c * 16 + cbase;
      int h = col & 511;
      float g = P[1024 + h];
      float bias = (col < 512) ? bhr[h] : bhi[h];
#pragma unroll
      for (int q = 0; q < 4; ++q) {
        int row = mb + wr * 64 + r * 16 + rbase + q;
        Hbuf[(size_t)row * 1024 + col] = f2bf(fmaf(acc[r][c][q], g, bias));
      }
    }
}

// ---------------- scan pass F: chunk finals ----------------
__global__ __launch_bounds__(512) void k_scanF(
    const float* __restrict__ P, const u16* __restrict__ Hbuf,
    float* __restrict__ finr, float* __restrict__ fini) {
  const int h = threadIdx.x;
  const int b = blockIdx.x, c = blockIdx.y;
  const float lr = P[h], li = P[512 + h];
  float hr = 0.f, hi = 0.f;
  size_t base = ((size_t)b * TT + (size_t)c * LCH) * 1024 + h;
  for (int j = 0; j < LCH; ++j) {
    float dr = bf2f(Hbuf[base]);
    float di = bf2f(Hbuf[base + 512]);
    float nr = fmaf(lr, hr, fmaf(-li, hi, dr));
    float ni = fmaf(lr, hi, fmaf(li, hr, di));
    hr = nr; hi = ni;
    base += 1024;
  }
  size_t f = ((size_t)b * NCH + c) * 512 + h;
  finr[f] = hr; fini[f] = hi;
}

// ---------------- carry chain ----------------
__global__ __launch_bounds__(512) void k_carry(
    const float* __restrict__ P, const float* __restrict__ finr,
    const float* __restrict__ fini, float* __restrict__ carr,
    float* __restrict__ cari) {
  const int h = threadIdx.x;
  const int b = blockIdx.x;
  const float Lr = P[1536 + h], Li = P[2048 + h];
  float cr = 0.f, ci = 0.f;
  for (int c = 0; c < NCH; ++c) {
    size_t idx = ((size_t)b * NCH + c) * 512 + h;
    carr[idx] = cr; cari[idx] = ci;
    float fr = finr[idx], fi = fini[idx];
    float nr = fmaf(Lr, cr, fmaf(-Li, ci, fr));
    float ni = fmaf(Lr, ci, fmaf(Li, cr, fi));
    cr = nr; ci = ni;
  }
}

// ---------------- scan pass W: rescan with carry, overwrite Hbuf ----------------
__global__ __launch_bounds__(512) void k_scanW(
    const float* __restrict__ P, u16* __restrict__ Hbuf,
    const float* __restrict__ carr, const float* __restrict__ cari) {
  const int h = threadIdx.x;
  const int b = blockIdx.x, c = blockIdx.y;
  const float lr = P[h], li = P[512 + h];
  size_t cidx = ((size_t)b * NCH + c) * 512 + h;
  float hr = carr[cidx], hi = cari[cidx];  // exact state entering chunk
  size_t base = ((size_t)b * TT + (size_t)c * LCH) * 1024 + h;
  for (int j = 0; j < LCH; ++j) {
    float dr = bf2f(Hbuf[base]);
    float di = bf2f(Hbuf[base + 512]);
    float nr = fmaf(lr, hr, fmaf(-li, hi, dr));
    float ni = fmaf(lr, hi, fmaf(li, hr, di));
    hr = nr; hi = ni;
    Hbuf[base] = f2bf(hr);
    Hbuf[base + 512] = f2bf(hi);
    base += 1024;
  }
}

// ---------------- GEMM2: Y = [Hre|Him|Xb] @ Ccat^T + bias ----------------
__global__ __launch_bounds__(256) void k_gemm2(
    const u16* __restrict__ Hbuf, const u16* __restrict__ Xb,
    const u16* __restrict__ Ccat, const float* __restrict__ bo,
    float* __restrict__ Y) {
  __shared__ __align__(16) char smem[2 * 128 * 64 * 2];
  char* sA = smem;
  char* sB = smem + 128 * 64 * 2;
  const int tid = threadIdx.x;
  const int lane = tid & 63;
  const int wid = tid >> 6;
  const int wr = wid >> 1, wc = wid & 1;
  const int mb = blockIdx.x * 128;
  const int nb = blockIdx.y * 128;

  f32x4 acc[4][4];
#pragma unroll
  for (int r = 0; r < 4; ++r)
#pragma unroll
    for (int c = 0; c < 4; ++c) acc[r][c] = (f32x4)0.f;

  for (int kt = 0; kt < 20; ++kt) {
    const int k0 = kt * 64;
    const u16* Asrc;
    size_t lda;
    int ka;
    if (kt < 16) { Asrc = Hbuf; lda = 1024; ka = k0; }
    else         { Asrc = Xb;   lda = 256;  ka = k0 - 1024; }
    __syncthreads();
#pragma unroll
    for (int i = 0; i < 4; ++i) {
      int s = i * 256 + tid;
      int row = s >> 3, slot = s & 7;
      int4 va = *(const int4*)(Asrc + (size_t)(mb + row) * lda + ka + slot * 8);
      int4 vb = *(const int4*)(Ccat + (size_t)(nb + row) * 1280 + k0 + slot * 8);
      int soff = row * 128 + ((slot ^ (row & 7)) << 4);
      *(int4*)(sA + soff) = va;
      *(int4*)(sB + soff) = vb;
    }
    __syncthreads();
#pragma unroll
    for (int kk = 0; kk < 2; ++kk) {
      bf16x8 af[4], bfr[4];
#pragma unroll
      for (int r = 0; r < 4; ++r) {
        int row = wr * 64 + r * 16 + (lane & 15);
        int slot = (kk * 4 + (lane >> 4)) ^ (row & 7);
        af[r] = *(const bf16x8*)(sA + row * 128 + slot * 16);
      }
#pragma unroll
      for (int c = 0; c < 4; ++c) {
        int row = wc * 64 + c * 16 + (lane & 15);
        int slot = (kk * 4 + (lane >> 4)) ^ (row & 7);
        bfr[c] = *(const bf16x8*)(sB + row * 128 + slot * 16);
      }
#pragma unroll
      for (int r = 0; r < 4; ++r)
#pragma unroll
        for (int c = 0; c < 4; ++c)
          acc[r][c] = __builtin_amdgcn_mfma_f32_16x16x32_bf16(af[r], bfr[c],
                                                              acc[r][c], 0, 0, 0);
    }
  }
  const int rbase = (lane >> 4) * 4;
  const int cbase = lane & 15;
#pragma unroll
  for (int r = 0; r < 4; ++r)
#pragma unroll
    for (int c = 0; c < 4; ++c) {
      int col = nb + wc * 64 + c * 16 + cbase;
      float bias = bo[col];
#pragma unroll
      for (int q = 0; q < 4; ++q) {
        int row = mb + wr * 64 + r * 16 + rbase + q;
        Y[(size_t)row * 256 + col] = acc[r][c][q] + bias;
      }
    }
}

extern "C" void kernel_launch(void* const* d_in, const int* in_sizes, int n_in,
                              void* d_out, int out_size, void* d_ws, size_t ws_size,
                              hipStream_t stream) {
  const float* X        = (const float*)d_in[0];
  const float* nu_log   = (const float*)d_in[1];
  const float* theta_lg = (const float*)d_in[2];
  const float* Bre      = (const float*)d_in[3];
  const float* Bim      = (const float*)d_in[4];
  const float* Cre      = (const float*)d_in[5];
  const float* Cim      = (const float*)d_in[6];
  const float* D        = (const float*)d_in[7];
  const float* bhr      = (const float*)d_in[8];
  const float* bhi      = (const float*)d_in[9];
  const float* bo       = (const float*)d_in[10];
  float* Y = (float*)d_out;
  char* ws = (char*)d_ws;

  // byte layout (all 256B aligned)
  size_t off = 0;
  float* P = (float*)(ws + off);            off += 2560 * 4;            // 10 KiB
  off = (off + 255) & ~(size_t)255;
  u16* Hbuf = (u16*)(ws + off);             off += (size_t)MM * 1024 * 2;  // 128 MiB
  u16* Xb   = (u16*)(ws + off);             off += (size_t)MM * 256 * 2;   // 32 MiB
  u16* Bcat = (u16*)(ws + off);             off += 1024 * 256 * 2;
  u16* Ccat = (u16*)(ws + off);             off += 256 * 1280 * 2;
  float* finr = (float*)(ws + off);         off += (size_t)BATCHN * NCH * 512 * 4;
  float* fini = (float*)(ws + off);         off += (size_t)BATCHN * NCH * 512 * 4;
  float* carr = (float*)(ws + off);         off += (size_t)BATCHN * NCH * 512 * 4;
  float* cari = (float*)(ws + off);         off += (size_t)BATCHN * NCH * 512 * 4;
  if (ws_size < off) return;  // ~170 MiB needed

  k_params<<<1, 512, 0, stream>>>(nu_log, theta_lg, P);
  k_prep_w<<<512, 256, 0, stream>>>(Bre, Bim, Cre, Cim, D, Bcat, Ccat);
  k_prep_x<<<MM * 256 / (256 * 8), 256, 0, stream>>>(X, Xb);
  k_gemm1<<<dim3(MM / 128, 8), 256, 0, stream>>>(Xb, Bcat, P, bhr, bhi, Hbuf);
  k_scanF<<<dim3(BATCHN, NCH), 512, 0, stream>>>(P, Hbuf, finr, fini);
  k_carry<<<BATCHN, 512, 0, stream>>>(P, finr, fini, carr, cari);
  k_scanW<<<dim3(BATCHN, NCH), 512, 0, stream>>>(P, Hbuf, carr, cari);
  k_gemm2<<<dim3(MM / 128, 2), 256, 0, stream>>>(Hbuf, Xb, Ccat, bo, Y);
}

// Round 4
// 324.219 us; speedup vs baseline: 1.0373x; 1.0373x over previous
//
#include <hip/hip_runtime.h>
#include <hip/hip_bf16.h>

// LRU forward, bf16-MFMA pipeline, round 3 (resubmit — round 3 bench never ran:
// GPU acquisition timeout).
//  drive = gamma*(X@B^T)+bias_h (complex); h_t = lam*h_{t-1}+d_t;
//  Y = Re(H@C^T) + X@D^T + bias_out.
// Round-3 change: scanW + gemm2 fused into k_fused2 (one block per (b,chunk)):
//  scan from exact f32 carry -> H chunk bf16 in LDS (never hits HBM) -> MFMA
//  vs Ccat (L2-resident, loaded as B-frags directly from global) + Xb tail.
// Removes ~384 MB of HBM traffic (scanW rw + gemm2 H read).
// Ccat K-order: [Cre[:,0:256] | -Cim[:,0:256] | Cre[:,256:512] | -Cim[:,256:512] | D]
// so each 512-wide half of K is produced by one scan pass (256 ch/thread-block).

#define TT     4096
#define BATCHN 16
#define MM     (BATCHN * TT)
#define LCH    64
#define NCH    (TT / LCH)

typedef unsigned short u16;
typedef short bf16x8 __attribute__((ext_vector_type(8)));
typedef float f32x4 __attribute__((ext_vector_type(4)));

__device__ __forceinline__ u16 f2bf(float f) {
  union { __hip_bfloat16 b; u16 u; } cv;
  cv.b = __float2bfloat16(f);
  return cv.u;
}
__device__ __forceinline__ float bf2f(u16 u) {
  union { u16 u; __hip_bfloat16 b; } cv;
  cv.u = u;
  return __bfloat162float(cv.b);
}

// ---------------- params ----------------
__global__ void k_params(const float* __restrict__ nu_log,
                         const float* __restrict__ theta_log,
                         float* __restrict__ P) {
  int h = threadIdx.x;
  if (h >= 512) return;
  double nu  = exp((double)nu_log[h]);
  double th  = exp((double)theta_log[h]);
  double mag = exp(-nu);
  double g   = sqrt(fmax(0.0, 1.0 - mag * mag));
  double magL = exp(-(double)LCH * nu);
  double aL   = (double)LCH * th;
  P[h]        = (float)(mag * cos(th));   // lam_re
  P[512 + h]  = (float)(mag * sin(th));   // lam_im
  P[1024 + h] = (float)g;                 // gamma
  P[1536 + h] = (float)(magL * cos(aL));  // lam^L re
  P[2048 + h] = (float)(magL * sin(aL));  // lam^L im
}

// ---------------- weight prep (bf16 concat, half-ordered Ccat) ----------------
__global__ void k_prep_w(const float* __restrict__ Bre, const float* __restrict__ Bim,
                         const float* __restrict__ Cre, const float* __restrict__ Cim,
                         const float* __restrict__ D, u16* __restrict__ Bcat,
                         u16* __restrict__ Ccat) {
  const int NB = 1024 * 256;
  const int NC = 256 * 1280;
  for (int idx = blockIdx.x * blockDim.x + threadIdx.x; idx < NB + NC;
       idx += gridDim.x * blockDim.x) {
    if (idx < NB) {
      int row = idx >> 8, col = idx & 255;
      float v = (row < 512) ? Bre[row * 256 + col] : Bim[(row - 512) * 256 + col];
      Bcat[idx] = f2bf(v);
    } else {
      int j = idx - NB;
      int o = j / 1280, k = j % 1280;
      float v;
      if (k < 1024) {
        int q = k >> 9, kk = k & 511;
        int h = q * 256 + (kk & 255);
        v = (kk < 256) ? Cre[o * 512 + h] : -Cim[o * 512 + h];
      } else {
        v = D[o * 256 + (k - 1024)];
      }
      Ccat[j] = f2bf(v);
    }
  }
}

// ---------------- X -> bf16 ----------------
__global__ __launch_bounds__(256) void k_prep_x(const float* __restrict__ X,
                                                u16* __restrict__ Xb) {
  int idx = blockIdx.x * 256 + threadIdx.x;
  const float4* s = (const float4*)X + (size_t)idx * 2;
  float4 a = s[0], b = s[1];
  u16 o[8] = {f2bf(a.x), f2bf(a.y), f2bf(a.z), f2bf(a.w),
              f2bf(b.x), f2bf(b.y), f2bf(b.z), f2bf(b.w)};
  *(int4*)(Xb + (size_t)idx * 8) = *(const int4*)o;
}

// ---------------- GEMM1: Hbuf(drive) = epi(Xb @ Bcat^T) ----------------
__global__ __launch_bounds__(256) void k_gemm1(
    const u16* __restrict__ Xb, const u16* __restrict__ Bcat,
    const float* __restrict__ P, const float* __restrict__ bhr,
    const float* __restrict__ bhi, u16* __restrict__ Hbuf) {
  __shared__ __align__(16) char smem[2 * 128 * 64 * 2];
  char* sA = smem;
  char* sB = smem + 128 * 64 * 2;
  const int tid = threadIdx.x;
  const int lane = tid & 63;
  const int wid = tid >> 6;
  const int wr = wid >> 1, wc = wid & 1;
  const int mb = blockIdx.x * 128;
  const int nb = blockIdx.y * 128;

  f32x4 acc[4][4];
#pragma unroll
  for (int r = 0; r < 4; ++r)
#pragma unroll
    for (int c = 0; c < 4; ++c) acc[r][c] = (f32x4)0.f;

  for (int kt = 0; kt < 4; ++kt) {
    const int k0 = kt * 64;
    __syncthreads();
#pragma unroll
    for (int i = 0; i < 4; ++i) {
      int s = i * 256 + tid;
      int row = s >> 3, slot = s & 7;
      int4 va = *(const int4*)(Xb + (size_t)(mb + row) * 256 + k0 + slot * 8);
      int4 vb = *(const int4*)(Bcat + (size_t)(nb + row) * 256 + k0 + slot * 8);
      int soff = row * 128 + ((slot ^ (row & 7)) << 4);
      *(int4*)(sA + soff) = va;
      *(int4*)(sB + soff) = vb;
    }
    __syncthreads();
#pragma unroll
    for (int kk = 0; kk < 2; ++kk) {
      bf16x8 af[4], bfr[4];
#pragma unroll
      for (int r = 0; r < 4; ++r) {
        int row = wr * 64 + r * 16 + (lane & 15);
        int slot = (kk * 4 + (lane >> 4)) ^ (row & 7);
        af[r] = *(const bf16x8*)(sA + row * 128 + slot * 16);
      }
#pragma unroll
      for (int c = 0; c < 4; ++c) {
        int row = wc * 64 + c * 16 + (lane & 15);
        int slot = (kk * 4 + (lane >> 4)) ^ (row & 7);
        bfr[c] = *(const bf16x8*)(sB + row * 128 + slot * 16);
      }
#pragma unroll
      for (int r = 0; r < 4; ++r)
#pragma unroll
        for (int c = 0; c < 4; ++c)
          acc[r][c] = __builtin_amdgcn_mfma_f32_16x16x32_bf16(af[r], bfr[c],
                                                              acc[r][c], 0, 0, 0);
    }
  }
  const int rbase = (lane >> 4) * 4;
  const int cbase = lane & 15;
#pragma unroll
  for (int r = 0; r < 4; ++r)
#pragma unroll
    for (int c = 0; c < 4; ++c) {
      int col = nb + wc * 64 + c * 16 + cbase;
      int h = col & 511;
      float g = P[1024 + h];
      float bias = (col < 512) ? bhr[h] : bhi[h];
#pragma unroll
      for (int q = 0; q < 4; ++q) {
        int row = mb + wr * 64 + r * 16 + rbase + q;
        Hbuf[(size_t)row * 1024 + col] = f2bf(fmaf(acc[r][c][q], g, bias));
      }
    }
}

// ---------------- scan pass F: chunk finals ----------------
__global__ __launch_bounds__(512) void k_scanF(
    const float* __restrict__ P, const u16* __restrict__ Hbuf,
    float* __restrict__ finr, float* __restrict__ fini) {
  const int h = threadIdx.x;
  const int b = blockIdx.x, c = blockIdx.y;
  const float lr = P[h], li = P[512 + h];
  float hr = 0.f, hi = 0.f;
  size_t base = ((size_t)b * TT + (size_t)c * LCH) * 1024 + h;
#pragma unroll 8
  for (int j = 0; j < LCH; ++j) {
    float dr = bf2f(Hbuf[base]);
    float di = bf2f(Hbuf[base + 512]);
    float nr = fmaf(lr, hr, fmaf(-li, hi, dr));
    float ni = fmaf(lr, hi, fmaf(li, hr, di));
    hr = nr; hi = ni;
    base += 1024;
  }
  size_t f = ((size_t)b * NCH + c) * 512 + h;
  finr[f] = hr; fini[f] = hi;
}

// ---------------- carry chain ----------------
__global__ __launch_bounds__(512) void k_carry(
    const float* __restrict__ P, const float* __restrict__ finr,
    const float* __restrict__ fini, float* __restrict__ carr,
    float* __restrict__ cari) {
  const int h = threadIdx.x;
  const int b = blockIdx.x;
  const float Lr = P[1536 + h], Li = P[2048 + h];
  float cr = 0.f, ci = 0.f;
  for (int c = 0; c < NCH; ++c) {
    size_t idx = ((size_t)b * NCH + c) * 512 + h;
    carr[idx] = cr; cari[idx] = ci;
    float fr = finr[idx], fi = fini[idx];
    float nr = fmaf(Lr, cr, fmaf(-Li, ci, fr));
    float ni = fmaf(Lr, ci, fmaf(Li, cr, fi));
    cr = nr; ci = ni;
  }
}

// ---------------- fused scan + output GEMM ----------------
// One block per (chunk c, batch b): 64 timesteps. 256 threads = 4 waves.
// Per K-half q (256 complex channels): scan in registers (1 ch/thread),
// H chunk bf16 -> LDS [64][512] (XOR-swizzled), then MFMA vs Ccat half.
// Tail: Xb tile [64][256] staged to LDS, MFMA vs D-part of Ccat.
__global__ __launch_bounds__(256) void k_fused2(
    const float* __restrict__ P, const u16* __restrict__ Hbuf,
    const u16* __restrict__ Xb, const u16* __restrict__ Ccat,
    const float* __restrict__ carr, const float* __restrict__ cari,
    const float* __restrict__ bo, float* __restrict__ Y) {
  __shared__ __align__(16) char Hs[64 * 1024];  // 64 KiB
  const int tid = threadIdx.x;
  const int lane = tid & 63;
  const int w = tid >> 6;            // wave = N-subtile (64 cols)
  const int c = blockIdx.x;
  const int b = blockIdx.y;
  const int row0 = b * TT + c * LCH;

  f32x4 acc[4][4];
#pragma unroll
  for (int m = 0; m < 4; ++m)
#pragma unroll
    for (int n = 0; n < 4; ++n) acc[m][n] = (f32x4)0.f;

#pragma unroll
  for (int q = 0; q < 2; ++q) {
    // ---- scan phase: channels h = q*256 + tid ----
    const int h = q * 256 + tid;
    const float lr = P[h], li = P[512 + h];
    size_t cidx = ((size_t)b * NCH + c) * 512 + h;
    float hr = carr[cidx], hi = cari[cidx];
    size_t base = (size_t)row0 * 1024 + h;
    __syncthreads();  // previous MFMA phase done reading Hs
#pragma unroll 8
    for (int j = 0; j < LCH; ++j) {
      float dr = bf2f(Hbuf[base]);
      float di = bf2f(Hbuf[base + 512]);
      float nr = fmaf(lr, hr, fmaf(-li, hi, dr));
      float ni = fmaf(lr, hi, fmaf(li, hr, di));
      hr = nr; hi = ni;
      // LDS[j][s] holds content col (s ^ (j&7))*8.. ; write col t at s=t^(j&7)
      int sre = ((tid >> 3) ^ (j & 7)) * 16 + (tid & 7) * 2;
      int sim = (((256 + tid) >> 3) ^ (j & 7)) * 16 + (tid & 7) * 2;
      *(u16*)(Hs + j * 1024 + sre) = f2bf(nr);
      *(u16*)(Hs + j * 1024 + sim) = f2bf(ni);
      base += 1024;
    }
    __syncthreads();
    // ---- MFMA phase: K-half q (512 wide) ----
#pragma unroll 4
    for (int ks = 0; ks < 16; ++ks) {
      bf16x8 af[4], bfr[4];
#pragma unroll
      for (int m = 0; m < 4; ++m) {
        int row = m * 16 + (lane & 15);
        int slot = (ks * 4 + (lane >> 4)) ^ (row & 7);
        af[m] = *(const bf16x8*)(Hs + row * 1024 + slot * 16);
      }
#pragma unroll
      for (int n = 0; n < 4; ++n) {
        int col = w * 64 + n * 16 + (lane & 15);
        bfr[n] = *(const bf16x8*)(Ccat + (size_t)col * 1280 + q * 512 +
                                  ks * 32 + (lane >> 4) * 8);
      }
#pragma unroll
      for (int m = 0; m < 4; ++m)
#pragma unroll
        for (int n = 0; n < 4; ++n)
          acc[m][n] = __builtin_amdgcn_mfma_f32_16x16x32_bf16(af[m], bfr[n],
                                                              acc[m][n], 0, 0, 0);
    }
  }

  // ---- X tail: stage Xb [64][256] (swizzled), MFMA vs D columns ----
  __syncthreads();
#pragma unroll
  for (int i = 0; i < 8; ++i) {
    int p = i * 256 + tid;              // 16B unit, 32 slots/row
    int row = p >> 5, slot = p & 31;
    int4 v = *(const int4*)(Xb + (size_t)(row0 + row) * 256 +
                            ((slot ^ (row & 7)) * 8));
    *(int4*)(Hs + row * 512 + slot * 16) = v;
  }
  __syncthreads();
#pragma unroll 2
  for (int ks = 0; ks < 8; ++ks) {
    bf16x8 af[4], bfr[4];
#pragma unroll
    for (int m = 0; m < 4; ++m) {
      int row = m * 16 + (lane & 15);
      int slot = (ks * 4 + (lane >> 4)) ^ (row & 7);
      af[m] = *(const bf16x8*)(Hs + row * 512 + slot * 16);
    }
#pragma unroll
    for (int n = 0; n < 4; ++n) {
      int col = w * 64 + n * 16 + (lane & 15);
      bfr[n] = *(const bf16x8*)(Ccat + (size_t)col * 1280 + 1024 +
                                ks * 32 + (lane >> 4) * 8);
    }
#pragma unroll
    for (int m = 0; m < 4; ++m)
#pragma unroll
      for (int n = 0; n < 4; ++n)
        acc[m][n] = __builtin_amdgcn_mfma_f32_16x16x32_bf16(af[m], bfr[n],
                                                            acc[m][n], 0, 0, 0);
  }

  // ---- epilogue: Y = acc + bias ----
  const int rb = (lane >> 4) * 4;
  const int cb = lane & 15;
#pragma unroll
  for (int m = 0; m < 4; ++m)
#pragma unroll
    for (int n = 0; n < 4; ++n) {
      int col = w * 64 + n * 16 + cb;
      float bias = bo[col];
#pragma unroll
      for (int qq = 0; qq < 4; ++qq) {
        int row = row0 + m * 16 + rb + qq;
        Y[(size_t)row * 256 + col] = acc[m][n][qq] + bias;
      }
    }
}

extern "C" void kernel_launch(void* const* d_in, const int* in_sizes, int n_in,
                              void* d_out, int out_size, void* d_ws, size_t ws_size,
                              hipStream_t stream) {
  const float* X        = (const float*)d_in[0];
  const float* nu_log   = (const float*)d_in[1];
  const float* theta_lg = (const float*)d_in[2];
  const float* Bre      = (const float*)d_in[3];
  const float* Bim      = (const float*)d_in[4];
  const float* Cre      = (const float*)d_in[5];
  const float* Cim      = (const float*)d_in[6];
  const float* D        = (const float*)d_in[7];
  const float* bhr      = (const float*)d_in[8];
  const float* bhi      = (const float*)d_in[9];
  const float* bo       = (const float*)d_in[10];
  float* Y = (float*)d_out;
  char* ws = (char*)d_ws;

  size_t off = 0;
  float* P = (float*)(ws + off);            off += 2560 * 4;
  off = (off + 255) & ~(size_t)255;
  u16* Hbuf = (u16*)(ws + off);             off += (size_t)MM * 1024 * 2;  // 128 MiB
  u16* Xb   = (u16*)(ws + off);             off += (size_t)MM * 256 * 2;   // 32 MiB
  u16* Bcat = (u16*)(ws + off);             off += 1024 * 256 * 2;
  u16* Ccat = (u16*)(ws + off);             off += 256 * 1280 * 2;
  float* finr = (float*)(ws + off);         off += (size_t)BATCHN * NCH * 512 * 4;
  float* fini = (float*)(ws + off);         off += (size_t)BATCHN * NCH * 512 * 4;
  float* carr = (float*)(ws + off);         off += (size_t)BATCHN * NCH * 512 * 4;
  float* cari = (float*)(ws + off);         off += (size_t)BATCHN * NCH * 512 * 4;
  if (ws_size < off) return;

  k_params<<<1, 512, 0, stream>>>(nu_log, theta_lg, P);
  k_prep_w<<<512, 256, 0, stream>>>(Bre, Bim, Cre, Cim, D, Bcat, Ccat);
  k_prep_x<<<MM * 256 / (256 * 8), 256, 0, stream>>>(X, Xb);
  k_gemm1<<<dim3(MM / 128, 8), 256, 0, stream>>>(Xb, Bcat, P, bhr, bhi, Hbuf);
  k_scanF<<<dim3(BATCHN, NCH), 512, 0, stream>>>(P, Hbuf, finr, fini);
  k_carry<<<BATCHN, 512, 0, stream>>>(P, finr, fini, carr, cari);
  k_fused2<<<dim3(NCH, BATCHN), 256, 0, stream>>>(P, Hbuf, Xb, Ccat, carr, cari,
                                                  bo, Y);
}